// Round 1
// baseline (2006.574 us; speedup 1.0000x reference)
//
#include <hip/hip_runtime.h>
#include <hip/hip_bf16.h>
#include <stdint.h>

// Chebyshev KAN: two layers of  out[b,o] = sum_{i,d} T_d(xhat[b,i]) * C[i,o,d]
// GEMM with virtual A (Chebyshev built on the fly) and repacked bf16 B.
// Round 5: counted-vmcnt pipeline (T3+T4). B is now TRIPLE buffered; the
// per-stage __syncthreads (which drained vmcnt(0) and ate DMA latency every
// stage) is replaced by raw s_barrier + counted s_waitcnt vmcnt(N), so two
// stages of global_load_lds stay in flight across barriers. s_setprio(1)
// wraps the MFMA cluster (T5).
// Block tile 128x256, wave tile 64x128, stage = 32 k (1 degree).

constexpr int BATCH   = 16384;
constexpr int IN_DIM  = 1024;
constexpr int HID_DIM = 2048;
constexpr int OUT_DIM = 1024;
#define DP1 9  // degree+1

using bf16_t = __hip_bfloat16;

typedef __attribute__((ext_vector_type(4))) float f32x4;
typedef __attribute__((ext_vector_type(8))) short s16x8;
typedef __attribute__((ext_vector_type(16))) float f32x16;
typedef __attribute__((ext_vector_type(16))) __bf16 bf16x16;

#define WAITV(N) asm volatile("s_waitcnt vmcnt(" #N ")" ::: "memory")
#define WAITL()  asm volatile("s_waitcnt lgkmcnt(0)" ::: "memory")

static __device__ __forceinline__ unsigned int f2bf_u(float f) {
  union { __hip_bfloat16 h; unsigned short u; } cv;
  cv.h = __float2bfloat16(f);
  return (unsigned int)cv.u;
}

// ---------------- min/max over batch, per column (two stage) ----------------
template <typename T>
__global__ void kan_minmax_partial(const T* __restrict__ x, int rows, int cols,
                                   float* __restrict__ mnp, float* __restrict__ mxp) {
  const int c  = blockIdx.x * 64 + (threadIdx.x & 63);
  const int rg = threadIdx.x >> 6;
  const int P  = gridDim.y;
  const int chunk = rows / P;
  const int r0 = blockIdx.y * chunk;
  float mn = 1e30f, mx = -1e30f;
  for (int r = r0 + rg; r < r0 + chunk; r += 4) {
    float v = (float)x[(size_t)r * cols + c];
    mn = fminf(mn, v); mx = fmaxf(mx, v);
  }
  __shared__ float smn[256], smx[256];
  smn[threadIdx.x] = mn; smx[threadIdx.x] = mx;
  __syncthreads();
  if (rg == 0) {
    int t = threadIdx.x;
    mn = fminf(fminf(smn[t], smn[t + 64]), fminf(smn[t + 128], smn[t + 192]));
    mx = fmaxf(fmaxf(smx[t], smx[t + 64]), fmaxf(smx[t + 128], smx[t + 192]));
    mnp[(size_t)blockIdx.y * cols + c] = mn;
    mxp[(size_t)blockIdx.y * cols + c] = mx;
  }
}

__global__ void kan_minmax_finalize(const float* __restrict__ mnp, const float* __restrict__ mxp,
                                    int cols, int P, float* __restrict__ s, float* __restrict__ t) {
  int c = blockIdx.x * blockDim.x + threadIdx.x;
  if (c >= cols) return;
  float mn = 1e30f, mx = -1e30f;
  for (int p = 0; p < P; ++p) {
    mn = fminf(mn, mnp[(size_t)p * cols + c]);
    mx = fmaxf(mx, mxp[(size_t)p * cols + c]);
  }
  float inv = 2.0f / (mx - mn);
  s[c] = inv;
  t[c] = -mn * inv - 1.0f;
}

// ---- repack coeffs [I,O,9] fp32 -> Bp in B-fragment order, bf16 ----
// One block owns ALL 9 d-slabs of an (ntile, ib) pair, so the stride-9
// gather reads each cache line once (d-neighbors hit L1) instead of 9x HBM.
// slab = (ntile*NIB + ib)*9 + d ; within slab chunk c = ng*64 + quad*16 + l16:
//   o = ntile*256 + ng*16 + l16 ; i = ib*32 + quad*8 + j
__global__ void kan_repack(const float* __restrict__ coeffs, int I, int O,
                           bf16_t* __restrict__ Bp) {
  const int NIB = I / 32;
  const int ib = blockIdx.x % NIB;
  const int ntile = blockIdx.x / NIB;
  const size_t slab0 = (size_t)(ntile * NIB + ib) * 9 * 8192;  // bf16 elems
  for (int c = threadIdx.x; c < 1024; c += 256) {
    const int l16  = c & 15;
    const int quad = (c >> 4) & 3;
    const int ng   = c >> 6;
    const int o = ntile * 256 + ng * 16 + l16;
    const int ibase = ib * 32 + quad * 8;
    float v[8][9];
#pragma unroll
    for (int q = 0; q < 8; ++q) {
      const float* rp = coeffs + ((size_t)(ibase + q) * O + o) * DP1;
#pragma unroll
      for (int d = 0; d < 9; ++d) v[q][d] = rp[d];
    }
#pragma unroll
    for (int d = 0; d < 9; ++d) {
      unsigned int pk[4];
#pragma unroll
      for (int q = 0; q < 4; ++q)
        pk[q] = f2bf_u(v[2 * q][d]) | (f2bf_u(v[2 * q + 1][d]) << 16);
      *reinterpret_cast<uint4*>(reinterpret_cast<char*>(Bp) +
          (slab0 + (size_t)d * 8192 + (size_t)c * 8) * 2) =
          make_uint4(pk[0], pk[1], pk[2], pk[3]);
    }
  }
}

// ---------------- fused Chebyshev-expand + bf16 MFMA GEMM ----------------
// block tile 128(m) x 256(n); 4 waves 2x2; wave tile 64x128 (acc 4x8).
// A: 2x8 KB double buffer (fragment order, produced by VALU).
// B: 3x16 KB TRIPLE buffer via global_load_lds, issued 2 stages ahead.
// Per iteration s: issue dma(s+2); produce A(s+1); read frags + 32 MFMA of
// stage s; then counted vmcnt (drain OWN dma(s+1) only, leave dma(s+2)+x
// prefetch in flight) + lgkmcnt(0) + raw s_barrier. vmcnt never hits 0 in
// the steady-state loop.
template <typename AT, typename OT>
__launch_bounds__(256, 2)
__global__ void kan_cheby_gemm(const AT* __restrict__ X, const bf16_t* __restrict__ Bp,
                               const float* __restrict__ sc, const float* __restrict__ tc,
                               OT* __restrict__ out, int I, int N) {
  __shared__ __align__(16) short Als[2][4096];     // 2x 8 KB: 128 rows x 32 k
  __shared__ __align__(16) short Bls[3][8192];     // 3x16 KB: 256 cols x 32 k

  const int m0   = blockIdx.x * 128;
  const int tid  = threadIdx.x;
  const int lane = tid & 63;
  const int wave = tid >> 6;
  const int wr   = wave >> 1;          // m half
  const int wc   = wave & 1;           // n half
  const int wm4  = wr * 4;             // 16-row-group base (m)
  const int wn16 = wc * 8;             // 16-col-group base (n)
  const int quad = lane >> 4;
  const int l16  = lane & 15;

  // producer: thread owns row ma, features hf*16..+15 of the current 32-block
  const int ma = tid & 127;
  const int hf = tid >> 7;

  const int NIB = I / 32;
  const int nstage = NIB * 9;
  const size_t slab_base = (size_t)blockIdx.y * NIB * 9 * 8192;  // bf16 elems

  auto dma_b = [&](int ss, int buf) {
    const char* g = reinterpret_cast<const char*>(Bp + slab_base + (size_t)ss * 8192) +
                    wave * 4096 + lane * 16;
    char* l = reinterpret_cast<char*>(&Bls[buf][0]) + wave * 4096;
#pragma unroll
    for (int t = 0; t < 4; ++t)
      __builtin_amdgcn_global_load_lds(
          (const __attribute__((address_space(1))) void*)(g + t * 1024),
          (__attribute__((address_space(3))) void*)(l + t * 1024), 16, 0, 0);
  };

  uint4 rq[4];  // raw x bits (prefetched one ib ahead)
  auto load_raw = [&](int ibx) {
    const char* xp = reinterpret_cast<const char*>(
        X + (size_t)(m0 + ma) * I + ibx * 32 + hf * 16);
    if constexpr (sizeof(AT) == 4) {
      rq[0] = *reinterpret_cast<const uint4*>(xp +  0);
      rq[1] = *reinterpret_cast<const uint4*>(xp + 16);
      rq[2] = *reinterpret_cast<const uint4*>(xp + 32);
      rq[3] = *reinterpret_cast<const uint4*>(xp + 48);
    } else {
      rq[0] = *reinterpret_cast<const uint4*>(xp +  0);
      rq[1] = *reinterpret_cast<const uint4*>(xp + 16);
    }
  };

  f32x16 xv, Tm1, Tm2;
#pragma unroll
  for (int j = 0; j < 16; ++j) { xv[j] = 0.f; Tm1[j] = 0.f; Tm2[j] = 0.f; }

  auto unpack_norm = [&](int ibx) {
    const int fbase = ibx * 32 + hf * 16;
    float rv[16];
    const unsigned int* w = reinterpret_cast<const unsigned int*>(rq);
    if constexpr (sizeof(AT) == 4) {
#pragma unroll
      for (int j = 0; j < 16; ++j) rv[j] = __uint_as_float(w[j]);
    } else {
#pragma unroll
      for (int q = 0; q < 8; ++q) {
        rv[2 * q + 0] = __uint_as_float(w[q] << 16);
        rv[2 * q + 1] = __uint_as_float(w[q] & 0xffff0000u);
      }
    }
    const float4* sp = reinterpret_cast<const float4*>(sc + fbase);
    const float4* tp = reinterpret_cast<const float4*>(tc + fbase);
#pragma unroll
    for (int v = 0; v < 4; ++v) {
      float4 s4 = sp[v], t4 = tp[v];
      xv[4 * v + 0] = fmaf(rv[4 * v + 0], s4.x, t4.x);
      xv[4 * v + 1] = fmaf(rv[4 * v + 1], s4.y, t4.y);
      xv[4 * v + 2] = fmaf(rv[4 * v + 2], s4.z, t4.z);
      xv[4 * v + 3] = fmaf(rv[4 * v + 3], s4.w, t4.w);
    }
  };

  // write producer row tv into A buffer `buf` (fragment order, 2 chunks)
  auto write_a = [&](int buf, const f32x16& tv) {
    union { bf16x16 v; uint4 q[2]; } u;
    u.v = __builtin_convertvector(tv, bf16x16);  // v_cvt_pk_bf16_f32 on gfx950
    char* b = reinterpret_cast<char*>(&Als[buf][0]) +
              (ma >> 4) * 1024 + hf * 512 + (ma & 15) * 16;
    *reinterpret_cast<uint4*>(b)       = u.q[0];
    *reinterpret_cast<uint4*>(b + 256) = u.q[1];
  };

  f32x4 acc[4][8] = {};

  // ---- prologue: stage 0 is (ib=0, d=0) = all-ones row.
  // Issue order: x(ib0) prefetch (oldest), dma(0), dma(1). Drain through
  // dma(0) with vmcnt(4) (leaves dma(1) in flight), publish A0, barrier.
  load_raw(0);
  dma_b(0, 0);
  dma_b(1, 1);
  {
    f32x16 ones;
#pragma unroll
    for (int j = 0; j < 16; ++j) ones[j] = 1.0f;
    write_a(0, ones);
    Tm1 = ones;
  }
  WAITV(4);
  WAITL();
  __builtin_amdgcn_s_barrier();

  int dn = 1, ibn = 0;  // degree/ib of the NEXT stage to produce (t = s+1)
  int cb = 0, nb = 2;   // B buffer of stage s / of stage s+2
  for (int s = 0; s < nstage; ++s) {
    const bool have1 = (s + 1 < nstage);
    const bool have2 = (s + 2 < nstage);

    // ---- issue B DMA for stage s+2 (lands 2 barriers from now)
    if (have2) dma_b(s + 2, nb);

    // ---- produce stage s+1 into A[(s+1)&1]
    bool did_raw = false;
    if (have1) {
      f32x16 tv;
      if (dn == 0) {
#pragma unroll
        for (int j = 0; j < 16; ++j) tv[j] = 1.0f;
      } else if (dn == 1) {
        unpack_norm(ibn);                       // normalize prefetched raw
        if (ibn + 1 < NIB) { load_raw(ibn + 1); did_raw = true; }  // 8 stages early
        tv = xv;
      } else {
        tv = 2.0f * xv * Tm1 - Tm2;
      }
      Tm2 = Tm1; Tm1 = tv;
      write_a((s + 1) & 1, tv);
      if (++dn == DP1) { dn = 0; ++ibn; }
    }

    // ---- consume stage s: fragment reads + 32 MFMA
    {
      const char* Ab = reinterpret_cast<const char*>(&Als[s & 1][0]) + lane * 16;
      const char* Bb = reinterpret_cast<const char*>(&Bls[cb][0]) + lane * 16;
      s16x8 fa[4], fb[8];
#pragma unroll
      for (int mt = 0; mt < 4; ++mt)
        fa[mt] = *reinterpret_cast<const s16x8*>(Ab + (wm4 + mt) * 1024);
#pragma unroll
      for (int nt = 0; nt < 8; ++nt)
        fb[nt] = *reinterpret_cast<const s16x8*>(Bb + (wn16 + nt) * 1024);
      __builtin_amdgcn_s_setprio(1);
#pragma unroll
      for (int mt = 0; mt < 4; ++mt)
#pragma unroll
        for (int nt = 0; nt < 8; ++nt)
          acc[mt][nt] = __builtin_amdgcn_mfma_f32_16x16x32_bf16(
              fa[mt], fb[nt], acc[mt][nt], 0, 0, 0);
      __builtin_amdgcn_s_setprio(0);
    }

    // ---- counted drain + barrier: publish A(s+1) (lgkm) and B(s+1) (own
    // dma share). Newer in-flight kept alive: dma(s+2) [4] + this-iter x
    // prefetch [4 fp32 / 2 bf16]. FIFO drain of the oldest ops guarantees
    // dma(s+1) is complete at the counted wait.
    if (have1) {
      if (have2) {
        if (did_raw) {
          if constexpr (sizeof(AT) == 4) WAITV(8); else WAITV(6);
        } else {
          WAITV(4);
        }
      } else {
        WAITV(0);      // tail: nothing newer worth keeping in flight
      }
      WAITL();
      __builtin_amdgcn_s_barrier();
    }
    cb = (cb == 2) ? 0 : cb + 1;
    nb = (nb == 2) ? 0 : nb + 1;
  }

  // epilogue: C/D layout col = lane&15 (n), row = quad*4 + reg (m)
  const int n0 = blockIdx.y * 256;
#pragma unroll
  for (int mt = 0; mt < 4; ++mt) {
#pragma unroll
    for (int nt = 0; nt < 8; ++nt) {
      const int n = n0 + wc * 128 + nt * 16 + l16;
#pragma unroll
      for (int r = 0; r < 4; ++r) {
        const int m = m0 + wr * 64 + mt * 16 + quad * 4 + r;
        float v = acc[mt][nt][r];
        if constexpr (sizeof(OT) == 4)
          out[(size_t)m * N + n] = v;
        else
          out[(size_t)m * N + n] = __float2bfloat16(v);
      }
    }
  }
}

// ---------------- launcher ----------------
extern "C" void kernel_launch(void* const* d_in, const int* in_sizes, int n_in,
                              void* d_out, int out_size, void* d_ws, size_t ws_size,
                              hipStream_t stream) {
  const float* x  = (const float*)d_in[0];
  const float* c1 = (const float*)d_in[1];
  const float* c2 = (const float*)d_in[2];
  float* out = (float*)d_out;

  char* ws = (char*)d_ws;
  size_t off = 0;
  auto take = [&](size_t n) -> char* {
    char* p = ws + off;
    off += (n + 255) & ~(size_t)255;
    return p;
  };
  bf16_t* Bp1 = (bf16_t*)take((size_t)HID_DIM * IN_DIM  * DP1 * 2);  // 37.75 MB
  bf16_t* Bp2 = (bf16_t*)take((size_t)OUT_DIM * HID_DIM * DP1 * 2);  // 37.75 MB
  bf16_t* h   = (bf16_t*)take((size_t)BATCH * HID_DIM * 2);          // 67 MB
  float* s1  = (float*)take(IN_DIM  * 4);
  float* t1  = (float*)take(IN_DIM  * 4);
  float* s2  = (float*)take(HID_DIM * 4);
  float* t2  = (float*)take(HID_DIM * 4);
  float* mnp = (float*)take((size_t)16 * HID_DIM * 4);
  float* mxp = (float*)take((size_t)16 * HID_DIM * 4);

  // layer 1
  kan_minmax_partial<float><<<dim3(IN_DIM / 64, 16), 256, 0, stream>>>(x, BATCH, IN_DIM, mnp, mxp);
  kan_minmax_finalize<<<dim3(IN_DIM / 256), 256, 0, stream>>>(mnp, mxp, IN_DIM, 16, s1, t1);
  kan_repack<<<dim3((HID_DIM / 256) * (IN_DIM / 32)), 256, 0, stream>>>(c1, IN_DIM, HID_DIM, Bp1);
  kan_repack<<<dim3((OUT_DIM / 256) * (HID_DIM / 32)), 256, 0, stream>>>(c2, HID_DIM, OUT_DIM, Bp2);
  kan_cheby_gemm<float, bf16_t><<<dim3(BATCH / 128, HID_DIM / 256), 256, 0, stream>>>(
      x, Bp1, s1, t1, h, IN_DIM, HID_DIM);

  // layer 2
  kan_minmax_partial<bf16_t><<<dim3(HID_DIM / 64, 16), 256, 0, stream>>>(h, BATCH, HID_DIM, mnp, mxp);
  kan_minmax_finalize<<<dim3(HID_DIM / 256), 256, 0, stream>>>(mnp, mxp, HID_DIM, 16, s2, t2);
  kan_cheby_gemm<bf16_t, float><<<dim3(BATCH / 128, OUT_DIM / 256), 256, 0, stream>>>(
      h, Bp2, s2, t2, out, HID_DIM, OUT_DIM);
}

// Round 3
// 1912.938 us; speedup vs baseline: 1.0489x; 1.0489x over previous
//
#include <hip/hip_runtime.h>
#include <hip/hip_bf16.h>
#include <stdint.h>

// Chebyshev KAN: two layers of  out[b,o] = sum_{i,d} T_d(xhat[b,i]) * C[i,o,d]
// GEMM with virtual A (Chebyshev built on the fly) and repacked bf16 B.
// Round 7 (= round 6 resubmit, harness-hardened): round-4 single-barrier
// schedule. New vs round 4:
//  (a) d=0 slab eliminated: T_0==1 so its contribution is bias[o]=sum_i C[i,o,0].
//      Computed DETERMINISTICALLY: kan_repack LDS-reduces per-(ib,o) partials
//      into biasp, kan_bias_finalize sums over ib. No atomics, no memset.
//  (b) fragment ds_reads issued BEFORE produce-A VALU so MFMA (frag-dependent)
//      and produce (rq/Tm-dependent) are independent chains the scheduler can
//      overlap across pipes.
//  (c) sc/tc staged to LDS in prologue: removes the per-ib global-latency
//      stall (which also force-drained the in-flight B DMA via FIFO vmcnt).
// Block tile 128x256, wave tile 64x128, stage = 32 k (1 degree).

constexpr int BATCH   = 16384;
constexpr int IN_DIM  = 1024;
constexpr int HID_DIM = 2048;
constexpr int OUT_DIM = 1024;
#define DP1 9  // degree+1 (storage layout of input coeffs)

using bf16_t = __hip_bfloat16;

typedef __attribute__((ext_vector_type(4))) float f32x4;
typedef __attribute__((ext_vector_type(8))) short s16x8;
typedef __attribute__((ext_vector_type(16))) float f32x16;
typedef __attribute__((ext_vector_type(16))) __bf16 bf16x16;

static __device__ __forceinline__ unsigned int f2bf_u(float f) {
  union { __hip_bfloat16 h; unsigned short u; } cv;
  cv.h = __float2bfloat16(f);
  return (unsigned int)cv.u;
}

// ---------------- min/max over batch, per column (two stage) ----------------
template <typename T>
__global__ void kan_minmax_partial(const T* __restrict__ x, int rows, int cols,
                                   float* __restrict__ mnp, float* __restrict__ mxp) {
  const int c  = blockIdx.x * 64 + (threadIdx.x & 63);
  const int rg = threadIdx.x >> 6;
  const int P  = gridDim.y;
  const int chunk = rows / P;
  const int r0 = blockIdx.y * chunk;
  float mn = 1e30f, mx = -1e30f;
  for (int r = r0 + rg; r < r0 + chunk; r += 4) {
    float v = (float)x[(size_t)r * cols + c];
    mn = fminf(mn, v); mx = fmaxf(mx, v);
  }
  __shared__ float smn[256], smx[256];
  smn[threadIdx.x] = mn; smx[threadIdx.x] = mx;
  __syncthreads();
  if (rg == 0) {
    int t = threadIdx.x;
    mn = fminf(fminf(smn[t], smn[t + 64]), fminf(smn[t + 128], smn[t + 192]));
    mx = fmaxf(fmaxf(smx[t], smx[t + 64]), fmaxf(smx[t + 128], smx[t + 192]));
    mnp[(size_t)blockIdx.y * cols + c] = mn;
    mxp[(size_t)blockIdx.y * cols + c] = mx;
  }
}

__global__ void kan_minmax_finalize(const float* __restrict__ mnp, const float* __restrict__ mxp,
                                    int cols, int P, float* __restrict__ s, float* __restrict__ t) {
  int c = blockIdx.x * blockDim.x + threadIdx.x;
  if (c >= cols) return;
  float mn = 1e30f, mx = -1e30f;
  for (int p = 0; p < P; ++p) {
    mn = fminf(mn, mnp[(size_t)p * cols + c]);
    mx = fmaxf(mx, mxp[(size_t)p * cols + c]);
  }
  float inv = 2.0f / (mx - mn);
  s[c] = inv;
  t[c] = -mn * inv - 1.0f;
}

// ---- repack coeffs [I,O,9] fp32 -> Bp in B-fragment order, bf16 (d=1..8) ----
// One block owns ALL 9 d-slabs of an (ntile, ib) pair, so the stride-9
// gather reads each cache line once. d=0 is NOT stored: its contribution
// (T_0 == 1) goes to biasp[ib*O + o] (per-ib partial, LDS-reduced, no atomics).
// slab = (ntile*NIB + ib)*8 + (d-1) ; within slab chunk c = ng*64+quad*16+l16:
//   o = ntile*256 + ng*16 + l16 ; i = ib*32 + quad*8 + j
__global__ void kan_repack(const float* __restrict__ coeffs, int I, int O,
                           bf16_t* __restrict__ Bp, float* __restrict__ biasp) {
  const int NIB = I / 32;
  const int ib = blockIdx.x % NIB;
  const int ntile = blockIdx.x / NIB;
  const size_t slab0 = (size_t)(ntile * NIB + ib) * 8 * 8192;  // bf16 elems
  __shared__ float sb[1024];
  for (int c = threadIdx.x; c < 1024; c += 256) {
    const int l16  = c & 15;
    const int quad = (c >> 4) & 3;
    const int ng   = c >> 6;
    const int o = ntile * 256 + ng * 16 + l16;
    const int ibase = ib * 32 + quad * 8;
    float v[8][9];
#pragma unroll
    for (int q = 0; q < 8; ++q) {
      const float* rp = coeffs + ((size_t)(ibase + q) * O + o) * DP1;
#pragma unroll
      for (int d = 0; d < 9; ++d) v[q][d] = rp[d];
    }
    // d = 0 -> partial bias (8 i's of this chunk)
    float bsum = 0.f;
#pragma unroll
    for (int q = 0; q < 8; ++q) bsum += v[q][0];
    sb[c] = bsum;
    // d = 1..8 -> slabs 0..7
#pragma unroll
    for (int d = 1; d < 9; ++d) {
      unsigned int pk[4];
#pragma unroll
      for (int q = 0; q < 4; ++q)
        pk[q] = f2bf_u(v[2 * q][d]) | (f2bf_u(v[2 * q + 1][d]) << 16);
      *reinterpret_cast<uint4*>(reinterpret_cast<char*>(Bp) +
          (slab0 + (size_t)(d - 1) * 8192 + (size_t)c * 8) * 2) =
          make_uint4(pk[0], pk[1], pk[2], pk[3]);
    }
  }
  __syncthreads();
  {
    const int t = threadIdx.x;          // 0..255 ; o_local = t
    const int ng = t >> 4, l16 = t & 15;
    const float s = sb[ng * 64 + l16] + sb[ng * 64 + 16 + l16] +
                    sb[ng * 64 + 32 + l16] + sb[ng * 64 + 48 + l16];
    biasp[(size_t)ib * O + ntile * 256 + t] = s;
  }
}

__global__ void kan_bias_finalize(const float* __restrict__ biasp, int NIB, int O,
                                  float* __restrict__ bias) {
  const int o = blockIdx.x * blockDim.x + threadIdx.x;
  if (o >= O) return;
  float s = 0.f;
  for (int p = 0; p < NIB; ++p) s += biasp[(size_t)p * O + o];
  bias[o] = s;
}

// ---------------- fused Chebyshev-expand + bf16 MFMA GEMM ----------------
// block tile 128(m) x 256(n); 4 waves 2x2; wave tile 64x128 (acc 4x8).
// A: 2x8 KB double buffer (fragment order). B: 2x16 KB double buffer via
// global_load_lds. ONE barrier per stage (round-4 schedule): stage s MFMAs
// buffers [s&1] while producing A[(s+1)&1] and DMA-ing B[(s+1)&1].
// Stage index s: ib = s>>3, degree d = (s&7)+1  (d=0 handled as bias).
template <typename AT, typename OT>
__launch_bounds__(256, 2)
__global__ void kan_cheby_gemm(const AT* __restrict__ X, const bf16_t* __restrict__ Bp,
                               const float* __restrict__ sc, const float* __restrict__ tc,
                               const float* __restrict__ bias,
                               OT* __restrict__ out, int I, int N) {
  __shared__ __align__(16) short Als[2][4096];     // 2x 8 KB: 128 rows x 32 k
  __shared__ __align__(16) short Bls[2][8192];     // 2x16 KB: 256 cols x 32 k
  __shared__ __align__(16) float scl[2048];        // staged scale
  __shared__ __align__(16) float tcl[2048];        // staged shift

  const int m0   = blockIdx.x * 128;
  const int tid  = threadIdx.x;
  const int lane = tid & 63;
  const int wave = tid >> 6;
  const int wr   = wave >> 1;          // m half
  const int wc   = wave & 1;           // n half
  const int wm4  = wr * 4;             // 16-row-group base (m)
  const int wn16 = wc * 8;             // 16-col-group base (n)
  const int quad = lane >> 4;
  const int l16  = lane & 15;

  // producer: thread owns row ma, features hf*16..+15 of the current 32-block
  const int ma = tid & 127;
  const int hf = tid >> 7;

  const int NIB = I / 32;
  const int nstage = NIB * 8;
  const size_t slab_base = (size_t)blockIdx.y * NIB * 8 * 8192;  // bf16 elems

  auto dma_b = [&](int ss) {
    const char* g = reinterpret_cast<const char*>(Bp + slab_base + (size_t)ss * 8192) +
                    wave * 4096 + lane * 16;
    char* l = reinterpret_cast<char*>(&Bls[ss & 1][0]) + wave * 4096;
#pragma unroll
    for (int t = 0; t < 4; ++t)
      __builtin_amdgcn_global_load_lds(
          (const __attribute__((address_space(1))) void*)(g + t * 1024),
          (__attribute__((address_space(3))) void*)(l + t * 1024), 16, 0, 0);
  };

  uint4 rq[4];  // raw x bits (prefetched one ib ahead)
  auto load_raw = [&](int ibx) {
    const char* xp = reinterpret_cast<const char*>(
        X + (size_t)(m0 + ma) * I + ibx * 32 + hf * 16);
    if constexpr (sizeof(AT) == 4) {
      rq[0] = *reinterpret_cast<const uint4*>(xp +  0);
      rq[1] = *reinterpret_cast<const uint4*>(xp + 16);
      rq[2] = *reinterpret_cast<const uint4*>(xp + 32);
      rq[3] = *reinterpret_cast<const uint4*>(xp + 48);
    } else {
      rq[0] = *reinterpret_cast<const uint4*>(xp +  0);
      rq[1] = *reinterpret_cast<const uint4*>(xp + 16);
    }
  };

  f32x16 xv, Tm1, Tm2;
#pragma unroll
  for (int j = 0; j < 16; ++j) { xv[j] = 0.f; Tm1[j] = 0.f; Tm2[j] = 0.f; }

  // normalize prefetched raw with LDS-staged scale/shift
  auto unpack_norm = [&](int ibx) {
    const int fbase = ibx * 32 + hf * 16;
    float rv[16];
    const unsigned int* w = reinterpret_cast<const unsigned int*>(rq);
    if constexpr (sizeof(AT) == 4) {
#pragma unroll
      for (int j = 0; j < 16; ++j) rv[j] = __uint_as_float(w[j]);
    } else {
#pragma unroll
      for (int q = 0; q < 8; ++q) {
        rv[2 * q + 0] = __uint_as_float(w[q] << 16);
        rv[2 * q + 1] = __uint_as_float(w[q] & 0xffff0000u);
      }
    }
    const float4* sp = reinterpret_cast<const float4*>(&scl[fbase]);
    const float4* tp = reinterpret_cast<const float4*>(&tcl[fbase]);
#pragma unroll
    for (int v = 0; v < 4; ++v) {
      float4 s4 = sp[v], t4 = tp[v];
      xv[4 * v + 0] = fmaf(rv[4 * v + 0], s4.x, t4.x);
      xv[4 * v + 1] = fmaf(rv[4 * v + 1], s4.y, t4.y);
      xv[4 * v + 2] = fmaf(rv[4 * v + 2], s4.z, t4.z);
      xv[4 * v + 3] = fmaf(rv[4 * v + 3], s4.w, t4.w);
    }
  };

  // write producer row tv into A buffer `buf` (fragment order, 2 chunks)
  auto write_a = [&](int buf, const f32x16& tv) {
    union { bf16x16 v; uint4 q[2]; } u;
    u.v = __builtin_convertvector(tv, bf16x16);  // v_cvt_pk_bf16_f32 on gfx950
    char* b = reinterpret_cast<char*>(&Als[buf][0]) +
              (ma >> 4) * 1024 + hf * 512 + (ma & 15) * 16;
    *reinterpret_cast<uint4*>(b)       = u.q[0];
    *reinterpret_cast<uint4*>(b + 256) = u.q[1];
  };

  f32x4 acc[4][8] = {};

  // ---- prologue: stage sc/tc to LDS; stage 0 is (ib=0, d=1) = xhat row.
  for (int k = tid; k < I; k += 256) { scl[k] = sc[k]; tcl[k] = tc[k]; }
  load_raw(0);
  dma_b(0);
  __syncthreads();                      // publish scl/tcl
  unpack_norm(0);
  write_a(0, xv);
  Tm1 = xv;
#pragma unroll
  for (int j = 0; j < 16; ++j) Tm2[j] = 1.0f;   // T_0
  if (NIB > 1) load_raw(1);
  __syncthreads();                      // publish A0; B0 DMA drained

  for (int s = 0; s < nstage; ++s) {
    // ---- issue B DMA for stage s+1
    if (s + 1 < nstage) dma_b(s + 1);

    // ---- fragment reads for stage s FIRST (only depend on last barrier);
    // MFMA depends on these, produce-A depends on rq/Tm — independent chains.
    const char* Ab = reinterpret_cast<const char*>(&Als[s & 1][0]) + lane * 16;
    const char* Bb = reinterpret_cast<const char*>(&Bls[s & 1][0]) + lane * 16;
    s16x8 fa[4], fb[8];
#pragma unroll
    for (int mt = 0; mt < 4; ++mt)
      fa[mt] = *reinterpret_cast<const s16x8*>(Ab + (wm4 + mt) * 1024);
#pragma unroll
    for (int nt = 0; nt < 8; ++nt)
      fb[nt] = *reinterpret_cast<const s16x8*>(Bb + (wn16 + nt) * 1024);

    // ---- produce stage s+1 into A[(s+1)&1]
    if (s + 1 < nstage) {
      const int t = s + 1;
      f32x16 tv;
      if ((t & 7) == 0) {               // d=1 of a new ib
        const int ibn = t >> 3;
        unpack_norm(ibn);               // uses rq prefetched 8 stages ago
        if (ibn + 1 < NIB) load_raw(ibn + 1);
        tv = Tm1 = xv;
#pragma unroll
        for (int j = 0; j < 16; ++j) Tm2[j] = 1.0f;
      } else {
        tv = 2.0f * xv * Tm1 - Tm2;
        Tm2 = Tm1; Tm1 = tv;
      }
      write_a(t & 1, tv);
    }

    // ---- 32 MFMA for stage s
#pragma unroll
    for (int mt = 0; mt < 4; ++mt)
#pragma unroll
      for (int nt = 0; nt < 8; ++nt)
        acc[mt][nt] = __builtin_amdgcn_mfma_f32_16x16x32_bf16(
            fa[mt], fb[nt], acc[mt][nt], 0, 0, 0);

    __syncthreads();  // single barrier: publishes A/B[(s+1)&1], frees [s&1]
  }

  // epilogue: C/D layout col = lane&15 (n), row = quad*4 + reg (m); add bias
  const int n0 = blockIdx.y * 256;
  float bv[8];
#pragma unroll
  for (int nt = 0; nt < 8; ++nt)
    bv[nt] = bias[n0 + wc * 128 + nt * 16 + l16];
#pragma unroll
  for (int mt = 0; mt < 4; ++mt) {
#pragma unroll
    for (int nt = 0; nt < 8; ++nt) {
      const int n = n0 + wc * 128 + nt * 16 + l16;
#pragma unroll
      for (int r = 0; r < 4; ++r) {
        const int m = m0 + wr * 64 + mt * 16 + quad * 4 + r;
        float v = acc[mt][nt][r] + bv[nt];
        if constexpr (sizeof(OT) == 4)
          out[(size_t)m * N + n] = v;
        else
          out[(size_t)m * N + n] = __float2bfloat16(v);
      }
    }
  }
}

// ---------------- launcher ----------------
extern "C" void kernel_launch(void* const* d_in, const int* in_sizes, int n_in,
                              void* d_out, int out_size, void* d_ws, size_t ws_size,
                              hipStream_t stream) {
  const float* x  = (const float*)d_in[0];
  const float* c1 = (const float*)d_in[1];
  const float* c2 = (const float*)d_in[2];
  float* out = (float*)d_out;

  char* ws = (char*)d_ws;
  size_t off = 0;
  auto take = [&](size_t n) -> char* {
    char* p = ws + off;
    off += (n + 255) & ~(size_t)255;
    return p;
  };
  bf16_t* Bp1 = (bf16_t*)take((size_t)HID_DIM * IN_DIM  * 8 * 2);  // 33.5 MB
  bf16_t* Bp2 = (bf16_t*)take((size_t)OUT_DIM * HID_DIM * 8 * 2);  // 33.5 MB
  bf16_t* h   = (bf16_t*)take((size_t)BATCH * HID_DIM * 2);        // 67 MB
  float* s1  = (float*)take(IN_DIM  * 4);
  float* t1  = (float*)take(IN_DIM  * 4);
  float* s2  = (float*)take(HID_DIM * 4);
  float* t2  = (float*)take(HID_DIM * 4);
  float* b1  = (float*)take(HID_DIM * 4);
  float* b2  = (float*)take(OUT_DIM * 4);
  float* bp1 = (float*)take((size_t)(IN_DIM / 32)  * HID_DIM * 4); // 256 KB
  float* bp2 = (float*)take((size_t)(HID_DIM / 32) * OUT_DIM * 4); // 256 KB
  float* mnp = (float*)take((size_t)16 * HID_DIM * 4);
  float* mxp = (float*)take((size_t)16 * HID_DIM * 4);

  // layer 1
  kan_minmax_partial<float><<<dim3(IN_DIM / 64, 16), 256, 0, stream>>>(x, BATCH, IN_DIM, mnp, mxp);
  kan_minmax_finalize<<<dim3(IN_DIM / 256), 256, 0, stream>>>(mnp, mxp, IN_DIM, 16, s1, t1);
  kan_repack<<<dim3((HID_DIM / 256) * (IN_DIM / 32)), 256, 0, stream>>>(c1, IN_DIM, HID_DIM, Bp1, bp1);
  kan_bias_finalize<<<dim3(HID_DIM / 256), 256, 0, stream>>>(bp1, IN_DIM / 32, HID_DIM, b1);
  kan_repack<<<dim3((OUT_DIM / 256) * (HID_DIM / 32)), 256, 0, stream>>>(c2, HID_DIM, OUT_DIM, Bp2, bp2);
  kan_bias_finalize<<<dim3(OUT_DIM / 256), 256, 0, stream>>>(bp2, HID_DIM / 32, OUT_DIM, b2);
  kan_cheby_gemm<float, bf16_t><<<dim3(BATCH / 128, HID_DIM / 256), 256, 0, stream>>>(
      x, Bp1, s1, t1, b1, h, IN_DIM, HID_DIM);

  // layer 2
  kan_minmax_partial<bf16_t><<<dim3(HID_DIM / 64, 16), 256, 0, stream>>>(h, BATCH, HID_DIM, mnp, mxp);
  kan_minmax_finalize<<<dim3(HID_DIM / 256), 256, 0, stream>>>(mnp, mxp, HID_DIM, 16, s2, t2);
  kan_cheby_gemm<bf16_t, float><<<dim3(BATCH / 128, OUT_DIM / 256), 256, 0, stream>>>(
      h, Bp2, s2, t2, b2, out, HID_DIM, OUT_DIM);
}